// Round 1
// baseline (9452.811 us; speedup 1.0000x reference)
//
#include <hip/hip_runtime.h>
#include <math.h>

// Problem constants
constexpr int Bn  = 2;
constexpr int C   = 256;
constexpr int H   = 256;
constexpr int W   = 256;
constexpr int HW  = H * W;        // 65536
constexpr int CHW = C * HW;       // 16777216

// ---------------------------------------------------------------------------
// Kernel 1: dense 3x3 conv, SAME padding, NCHW, C=256 -> C=256.
// Block: 256 threads = 32(w) x 8(h) spatial tile, 16 output channels/block.
// Grid: 2(b) * 16(oc tiles) * 32(h tiles) * 8(w tiles) = 8192 blocks.
// ---------------------------------------------------------------------------
__global__ __launch_bounds__(256) void conv3x3_k(
    const float* __restrict__ x, const float* __restrict__ wt,
    float* __restrict__ out)
{
    __shared__ float tile[10][34];
    const int id  = blockIdx.x;
    const int tw  = id & 7;
    const int th  = (id >> 3) & 31;
    const int oct = (id >> 8) & 15;
    const int b   = id >> 12;
    const int w0 = tw * 32, h0 = th * 8, oc0 = oct * 16;
    const int t  = threadIdx.x;
    const int tx = t & 31, ty = t >> 5;

    float acc[16];
#pragma unroll
    for (int o = 0; o < 16; o++) acc[o] = 0.f;

    const float* xb = x + b * CHW;
    for (int ic = 0; ic < C; ic++) {
        const float* xc = xb + ic * HW;
        // stage 34x10 halo tile
        for (int i = t; i < 340; i += 256) {
            int r  = i / 34;
            int ci = i - r * 34;
            int hh = h0 + r - 1, ww = w0 + ci - 1;
            float v = 0.f;
            if ((unsigned)hh < (unsigned)H && (unsigned)ww < (unsigned)W)
                v = xc[hh * W + ww];
            tile[r][ci] = v;
        }
        __syncthreads();
        float in[9];
#pragma unroll
        for (int dy = 0; dy < 3; dy++)
#pragma unroll
            for (int dx = 0; dx < 3; dx++)
                in[dy * 3 + dx] = tile[ty + dy][tx + dx];
        const float* wc = wt + (oc0 * C + ic) * 9;
#pragma unroll
        for (int o = 0; o < 16; o++) {
            const float* wo = wc + o * C * 9;
#pragma unroll
            for (int kk = 0; kk < 9; kk++)
                acc[o] = fmaf(in[kk], wo[kk], acc[o]);
        }
        __syncthreads();
    }
    const int hh = h0 + ty, ww = w0 + tx;
#pragma unroll
    for (int o = 0; o < 16; o++)
        out[((b * C + oc0 + o) * H + hh) * W + ww] = acc[o];
}

// ---------------------------------------------------------------------------
// Kernel 2: training-mode BN stats per channel over (B,H,W); writes fused
// scale/shift:  y = x*scale + shift  where scale = g*rsqrt(var+eps),
// shift = beta - mean*scale.  One block per channel.
// ---------------------------------------------------------------------------
__global__ __launch_bounds__(256) void bnstats_k(
    const float* __restrict__ a, const float* __restrict__ g,
    const float* __restrict__ beta,
    float* __restrict__ scale, float* __restrict__ shift)
{
    const int c = blockIdx.x;
    const int t = threadIdx.x;
    float s = 0.f, ss = 0.f;
    for (int b = 0; b < Bn; b++) {
        const float4* p = (const float4*)(a + (size_t)(b * C + c) * HW);
        for (int i = t; i < HW / 4; i += 256) {
            float4 v = p[i];
            s  += v.x + v.y + v.z + v.w;
            ss += v.x * v.x + v.y * v.y + v.z * v.z + v.w * v.w;
        }
    }
    __shared__ float rs[256], rss[256];
    rs[t] = s; rss[t] = ss;
    __syncthreads();
    for (int o = 128; o > 0; o >>= 1) {
        if (t < o) { rs[t] += rs[t + o]; rss[t] += rss[t + o]; }
        __syncthreads();
    }
    if (t == 0) {
        const float n    = (float)(Bn * HW);
        const float mean = rs[0] / n;
        const float var  = rss[0] / n - mean * mean;
        const float sc   = g[c] * rsqrtf(var + 1e-5f);
        scale[c] = sc;
        shift[c] = beta[c] - mean * sc;
    }
}

// ---------------------------------------------------------------------------
// Kernel 3: depthwise 3x3 conv with BN+relu6 fused on the INPUT read.
// Padding is zero in the post-activation domain (matches reference: the
// depthwise conv pads iem_out with zeros).
// Grid: 2 * 256(c) * 32(h tiles) * 8(w tiles) = 131072 blocks.
// ---------------------------------------------------------------------------
__global__ __launch_bounds__(256) void dwconv_k(
    const float* __restrict__ a, const float* __restrict__ scale,
    const float* __restrict__ shift, const float* __restrict__ wd,
    float* __restrict__ out)
{
    __shared__ float tile[10][34];
    const int id = blockIdx.x;
    const int tw = id & 7;
    const int th = (id >> 3) & 31;
    const int c  = (id >> 8) & 255;
    const int b  = id >> 16;
    const int w0 = tw * 32, h0 = th * 8;
    const int t  = threadIdx.x;
    const int tx = t & 31, ty = t >> 5;
    const float sc = scale[c], sh = shift[c];
    const float* ac = a + (size_t)(b * C + c) * HW;

    for (int i = t; i < 340; i += 256) {
        int r  = i / 34;
        int ci = i - r * 34;
        int hh = h0 + r - 1, ww = w0 + ci - 1;
        float v = 0.f;
        if ((unsigned)hh < (unsigned)H && (unsigned)ww < (unsigned)W) {
            float u = fmaf(ac[hh * W + ww], sc, sh);
            v = fminf(fmaxf(u, 0.f), 6.f);
        }
        tile[r][ci] = v;
    }
    __syncthreads();
    const float* wc = wd + c * 9;
    float r = 0.f;
#pragma unroll
    for (int dy = 0; dy < 3; dy++)
#pragma unroll
        for (int dx = 0; dx < 3; dx++)
            r = fmaf(tile[ty + dy][tx + dx], wc[dy * 3 + dx], r);
    out[(size_t)(b * C + c) * HW + (h0 + ty) * W + (w0 + tx)] = r;
}

// ---------------------------------------------------------------------------
// Kernel 4: per-pixel mean over channels -> [B, H*W]
// ---------------------------------------------------------------------------
__global__ __launch_bounds__(256) void cmean_k(
    const float* __restrict__ m, float* __restrict__ s)
{
    const int px = blockIdx.x * 256 + threadIdx.x;  // 0 .. 2*HW-1
    const int b  = px >> 16;
    const int hw = px & (HW - 1);
    const float* p = m + (size_t)b * CHW + hw;
    float acc = 0.f;
#pragma unroll 4
    for (int c = 0; c < C; c++) acc += p[(size_t)c * HW];
    s[px] = acc * (1.f / C);
}

// ---------------------------------------------------------------------------
// Kernel 5: 1x1 conv / channel matmul: out[o][px] = sum_c W[o][c] * in[c][px]
// Block: 256 threads = 256 pixels; 64 out channels per block.
// Grid: 2(b) * 4(oc tiles) * 256(px blocks) = 2048 blocks.
// ---------------------------------------------------------------------------
__global__ __launch_bounds__(256) void chmm_k(
    const float* __restrict__ wmat, const float* __restrict__ in,
    float* __restrict__ out)
{
    const int id   = blockIdx.x;
    const int pblk = id & 255;
    const int oct  = (id >> 8) & 3;
    const int b    = id >> 10;
    const int px   = pblk * 256 + threadIdx.x;
    const int oc0  = oct * 64;
    const float* ip = in + (size_t)b * CHW + px;

    float acc[64];
#pragma unroll
    for (int o = 0; o < 64; o++) acc[o] = 0.f;

    for (int c = 0; c < C; c++) {
        const float v = ip[(size_t)c * HW];
        const float* wr = wmat + oc0 * C + c;
#pragma unroll
        for (int o = 0; o < 64; o++)
            acc[o] = fmaf(v, wr[o * C], acc[o]);
    }
    float* op = out + (size_t)b * CHW + px;
#pragma unroll
    for (int o = 0; o < 64; o++) op[(size_t)(oc0 + o) * HW] = acc[o];
}

// ---------------------------------------------------------------------------
// Kernel 6: windowed attention. One wave (64 threads) per (b, head, wy, wx).
// Thread t <-> window pixel p = t (iy = t/8, ix = t%8), both as query row and
// as key/value row owner. q row stays in registers; k, v go to LDS and are
// read back as wave-uniform (broadcast) float4 reads.
// All per-row scales (q L2 norm, 1+illum, clip(1-noise), temperature, d^-1/2)
// are folded multiplicatively into S.
// Grid: 2 * 8 * 32 * 32 = 16384 blocks.
// out may alias q (each block writes exactly the q window it already read).
// ---------------------------------------------------------------------------
__global__ __launch_bounds__(64) void attn_k(
    const float* __restrict__ q, const float* __restrict__ k,
    const float* __restrict__ v, const float* __restrict__ si,
    const float* __restrict__ sn, const float* __restrict__ temp,
    float* __restrict__ out)
{
    __shared__ __align__(16) float ks[64][36];
    __shared__ __align__(16) float vs[64][36];
    __shared__ float kscale[64];

    const int id   = blockIdx.x;
    const int wx   = id & 31;
    const int wy   = (id >> 5) & 31;
    const int head = (id >> 10) & 7;
    const int b    = id >> 13;
    const int t    = threadIdx.x;
    const int iy   = t >> 3, ix = t & 7;
    const int hh   = wy * 8 + iy, ww = wx * 8 + ix;
    const int pix  = hh * W + ww;
    const int ch0  = head * 32;

    // ---- load q row (registers), k row and v row (LDS), all for pixel t ----
    const float* qb = q + (size_t)(b * C + ch0) * HW + pix;
    const float* kb = k + (size_t)(b * C + ch0) * HW + pix;
    const float* vb = v + (size_t)(b * C + ch0) * HW + pix;

    float qr[32];
    float qss = 0.f, kss = 0.f;
#pragma unroll
    for (int dc = 0; dc < 32; dc++) {
        qr[dc] = qb[(size_t)dc * HW];
        qss += qr[dc] * qr[dc];
        float kvv = kb[(size_t)dc * HW];
        kss += kvv * kvv;
        ks[t][dc] = kvv;
        vs[t][dc] = vb[(size_t)dc * HW];
    }
    const float il = si[b * HW + pix];
    const float nz = sn[b * HW + pix];
    const float tscale = temp[head] * 0.17677669529663689f;  // 32^-0.5
    const float qmul = (1.f + il) / fmaxf(sqrtf(qss), 1e-12f) * tscale;
    kscale[t] = fminf(fmaxf(1.f - nz, 0.f), 1.f) / fmaxf(sqrtf(kss), 1e-12f);
    __syncthreads();

    // ---- S = q . k^T with folded scales ----
    float Srow[64];
#pragma unroll
    for (int kk = 0; kk < 64; kk++) {
        const float4* kr = (const float4*)(&ks[kk][0]);
        float d = 0.f;
#pragma unroll
        for (int j = 0; j < 8; j++) {
            float4 kv = kr[j];
            d = fmaf(qr[4 * j + 0], kv.x, d);
            d = fmaf(qr[4 * j + 1], kv.y, d);
            d = fmaf(qr[4 * j + 2], kv.z, d);
            d = fmaf(qr[4 * j + 3], kv.w, d);
        }
        Srow[kk] = d * qmul * kscale[kk];
    }

    // ---- softmax over kk ----
    float m = Srow[0];
#pragma unroll
    for (int kk = 1; kk < 64; kk++) m = fmaxf(m, Srow[kk]);
    float ssum = 0.f;
#pragma unroll
    for (int kk = 0; kk < 64; kk++) {
        float e = __expf(Srow[kk] - m);
        Srow[kk] = e;
        ssum += e;
    }
    const float inv = 1.f / ssum;

    // ---- O = P . V ----
    float4 oacc[8];
#pragma unroll
    for (int j = 0; j < 8; j++) oacc[j] = make_float4(0.f, 0.f, 0.f, 0.f);
#pragma unroll
    for (int kk = 0; kk < 64; kk++) {
        const float p = Srow[kk] * inv;
        const float4* vr = (const float4*)(&vs[kk][0]);
#pragma unroll
        for (int j = 0; j < 8; j++) {
            float4 vv = vr[j];
            oacc[j].x = fmaf(p, vv.x, oacc[j].x);
            oacc[j].y = fmaf(p, vv.y, oacc[j].y);
            oacc[j].z = fmaf(p, vv.z, oacc[j].z);
            oacc[j].w = fmaf(p, vv.w, oacc[j].w);
        }
    }
    float* ob = out + (size_t)(b * C + ch0) * HW + pix;
#pragma unroll
    for (int j = 0; j < 8; j++) {
        ob[(size_t)(4 * j + 0) * HW] = oacc[j].x;
        ob[(size_t)(4 * j + 1) * HW] = oacc[j].y;
        ob[(size_t)(4 * j + 2) * HW] = oacc[j].z;
        ob[(size_t)(4 * j + 3) * HW] = oacc[j].w;
    }
}

// ---------------------------------------------------------------------------
extern "C" void kernel_launch(void* const* d_in, const int* in_sizes, int n_in,
                              void* d_out, int out_size, void* d_ws, size_t ws_size,
                              hipStream_t stream)
{
    const float* x        = (const float*)d_in[0];
    const float* w_iem    = (const float*)d_in[1];
    const float* g_iem    = (const float*)d_in[2];
    const float* b_iem    = (const float*)d_in[3];
    const float* w_nem    = (const float*)d_in[4];
    const float* g_nem    = (const float*)d_in[5];
    const float* b_nem    = (const float*)d_in[6];
    const float* w_iem_dw = (const float*)d_in[7];
    const float* w_nem_dw = (const float*)d_in[8];
    const float* w_q      = (const float*)d_in[9];
    const float* w_k      = (const float*)d_in[10];
    const float* w_v      = (const float*)d_in[11];
    const float* w_proj   = (const float*)d_in[12];
    const float* temp     = (const float*)d_in[13];

    // workspace layout (floats): A | B | C | scale | shift | sI | sN
    float* A   = (float*)d_ws;          // 33554432
    float* Bf  = A  + (size_t)Bn * CHW; // 33554432
    float* Cf  = Bf + (size_t)Bn * CHW; // 33554432
    float* scl = Cf + (size_t)Bn * CHW; // 256
    float* shf = scl + 256;             // 256
    float* sI  = shf + 256;             // 131072
    float* sN  = sI + (size_t)Bn * HW;  // 131072

    // IEM path: conv -> BN stats -> (BN+relu6 fused) depthwise -> illum map (B)
    conv3x3_k<<<8192, 256, 0, stream>>>(x, w_iem, A);
    bnstats_k<<<256, 256, 0, stream>>>(A, g_iem, b_iem, scl, shf);
    dwconv_k<<<131072, 256, 0, stream>>>(A, scl, shf, w_iem_dw, Bf);

    // NEM path -> noise map (C)
    conv3x3_k<<<8192, 256, 0, stream>>>(x, w_nem, A);
    bnstats_k<<<256, 256, 0, stream>>>(A, g_nem, b_nem, scl, shf);
    dwconv_k<<<131072, 256, 0, stream>>>(A, scl, shf, w_nem_dw, Cf);

    // per-pixel channel means
    cmean_k<<<512, 256, 0, stream>>>(Bf, sI);
    cmean_k<<<512, 256, 0, stream>>>(Cf, sN);

    // projections: q = Wq*illum(B) -> A ; k = Wk*noise(C) -> B ; v = Wv*x -> C
    chmm_k<<<2048, 256, 0, stream>>>(w_q, Bf, A);
    chmm_k<<<2048, 256, 0, stream>>>(w_k, Cf, Bf);
    chmm_k<<<2048, 256, 0, stream>>>(w_v, x, Cf);

    // windowed attention (writes back into A, in-place over q)
    attn_k<<<16384, 64, 0, stream>>>(A, Bf, Cf, sI, sN, temp, A);

    // final projection -> d_out
    chmm_k<<<2048, 256, 0, stream>>>(w_proj, A, (float*)d_out);
}

// Round 2
// 1499.886 us; speedup vs baseline: 6.3024x; 6.3024x over previous
//
#include <hip/hip_runtime.h>
#include <math.h>

// ---------------------------------------------------------------------------
// Problem constants
constexpr int Bn  = 2;
constexpr int C   = 256;
constexpr int H   = 256;
constexpr int W   = 256;
constexpr int HW  = H * W;          // 65536
constexpr size_t CHW = (size_t)C * HW;

typedef __bf16 bf16x8 __attribute__((ext_vector_type(8)));
typedef float  f32x4  __attribute__((ext_vector_type(4)));

// fp32 -> bf16 round-to-nearest-even
__device__ __forceinline__ unsigned short f2bf(float f) {
    unsigned int u = __float_as_uint(f);
    u += 0x7fffu + ((u >> 16) & 1u);
    return (unsigned short)(u >> 16);
}
__device__ __forceinline__ float bf2f(unsigned short h) {
    return __uint_as_float(((unsigned int)h) << 16);
}
// two bf16 packed in a uint -> floats (hi needs only a mask)
__device__ __forceinline__ float bflo(unsigned int u) { return __uint_as_float(u << 16); }
__device__ __forceinline__ float bfhi(unsigned int u) { return __uint_as_float(u & 0xffff0000u); }

// async global->LDS, 16B per lane; LDS dest = uniform base + lane*16
__device__ __forceinline__ void gld_lds16(const void* g, void* lds) {
    __builtin_amdgcn_global_load_lds(
        (const __attribute__((address_space(1))) unsigned int*)g,
        (__attribute__((address_space(3))) unsigned int*)lds, 16, 0, 0);
}

// ---------------------------------------------------------------------------
// packx: x fp32 NCHW -> bf16 NHWC.  Tile 64c x 64px via LDS transpose.
// grid = (2*65536/64) * 4 = 8192 blocks
// ---------------------------------------------------------------------------
__global__ __launch_bounds__(256) void packx_k(
    const float* __restrict__ x, unsigned short* __restrict__ xT)
{
    __shared__ float tl[64][65];
    const int id = blockIdx.x;
    const int ct = id & 3;
    const size_t px0 = (size_t)(id >> 2) * 64;   // global pixel (incl batch)
    const int b  = (int)(px0 >> 16);
    const int hw = (int)(px0 & 65535);
    const int c0 = ct * 64;
    const int t  = threadIdx.x;

    {   // load: thread (cl, pseg): 16 px of channel cl
        const int cl = t >> 2, pseg = t & 3;
        const float* src = x + ((size_t)(b * C + c0 + cl)) * HW + hw + pseg * 16;
#pragma unroll
        for (int i = 0; i < 4; i++) {
            float4 v = *(const float4*)(src + i * 4);
            tl[cl][pseg * 16 + i * 4 + 0] = v.x;
            tl[cl][pseg * 16 + i * 4 + 1] = v.y;
            tl[cl][pseg * 16 + i * 4 + 2] = v.z;
            tl[cl][pseg * 16 + i * 4 + 3] = v.w;
        }
    }
    __syncthreads();
    {   // store: thread (pl, csec): 16 channels of pixel pl, contiguous in NHWC
        const int pl = t >> 2, csec = t & 3;
        __attribute__((aligned(16))) unsigned short rv[16];
#pragma unroll
        for (int j = 0; j < 16; j++) rv[j] = f2bf(tl[csec * 16 + j][pl]);
        unsigned short* dst = xT + (px0 + pl) * C + c0 + csec * 16;
        *(uint4*)dst       = *(const uint4*)&rv[0];
        *(uint4*)(dst + 8) = *(const uint4*)&rv[8];
    }
}

// ---------------------------------------------------------------------------
// pack weights into the LDS image the GEMM stages:
// layout [taps][oct(2)][icc(8)][ocl(128)][kslot(32)], with XOR-4 swizzle
// content(ocl, kslot) = W[oc][ icc*32 + ((kslot>>3) ^ ((ocl>>2)&3))*8 + (kslot&7) ]
// ---------------------------------------------------------------------------
__global__ __launch_bounds__(256) void pack_k(
    const float* __restrict__ w, unsigned short* __restrict__ out, int taps)
{
    const int e = blockIdx.x * 256 + threadIdx.x;
    const int kslot = e & 31;
    const int ocl   = (e >> 5) & 127;
    const int icc   = (e >> 12) & 7;
    const int oct   = (e >> 15) & 1;
    const int off   = e >> 16;
    const int oc = oct * 128 + ocl;
    const int q  = kslot >> 3, j = kslot & 7;
    const int ic = icc * 32 + ((q ^ ((ocl >> 2) & 3)) << 3) + j;
    out[e] = f2bf(w[((size_t)oc * C + ic) * taps + off]);
}

// ---------------------------------------------------------------------------
// MFMA GEMM: out[oc][px] = sum_k Wp[oc][k] * B[k][px]
//  NOFF==9: implicit 3x3 conv (K = 256ic x 9 taps), B = xT shifted (zero pad)
//  NOFF==1: 1x1 conv (K = 256)
// B input: NHWC bf16.  Output: NCHW (bf16 or fp32).
// Block: 256 thr = 4 waves (2x2), tile 128oc x 128px (one image row segment).
// grid = 2048:  id = oct | ch<<1 | r<<2 | b<<10
// ---------------------------------------------------------------------------
template<int NOFF, bool F32OUT>
__global__ __launch_bounds__(256, 2) void gemm_k(
    const unsigned short* __restrict__ xT, const unsigned short* __restrict__ Wp,
    unsigned short* __restrict__ outb, float* __restrict__ outf,
    const unsigned short* __restrict__ zbuf)
{
    __shared__ unsigned short As[128 * 32];   // [ocl][kslot]  8KB
    __shared__ unsigned short Bs[128 * 32];   // [px][kslot]   8KB

    const int id  = blockIdx.x;
    const int oct = id & 1;
    const int ch  = (id >> 1) & 1;
    const int r   = (id >> 2) & 255;
    const int b   = id >> 10;
    const int px0 = ch * 128;

    const int t  = threadIdx.x;
    const int wv = t >> 6;
    const int l  = t & 63;
    const int wm = (wv >> 1) * 64;
    const int wn = (wv & 1) * 64;

    // swizzled quad for frag reads
    const int qp = (l >> 4) ^ ((l >> 2) & 3);
    int a_off[4], b_off[4];
#pragma unroll
    for (int i = 0; i < 4; i++) {
        a_off[i] = (wm + i * 16 + (l & 15)) * 64 + qp * 16;   // bytes
        b_off[i] = (wn + i * 16 + (l & 15)) * 64 + qp * 16;
    }
    // B staging: lane l stages LDS slot row px=(wv*32+i*16+(l>>2)), quad (l&3)
    const int spx_base = wv * 32 + (l >> 2);
    const int skk0 = (((l & 3) ^ (l >> 4)) << 3);            // source k-group (elems)

    f32x4 acc[4][4];
#pragma unroll
    for (int i = 0; i < 4; i++)
#pragma unroll
        for (int j = 0; j < 4; j++) acc[i][j] = (f32x4){0.f, 0.f, 0.f, 0.f};

    char* AsB = (char*)As + wv * 2048;
    char* BsB = (char*)Bs + wv * 2048;

#pragma unroll 1
    for (int off = 0; off < NOFF; ++off) {
        int dy = 1, dx = 1, rr = r;
        if (NOFF == 9) {
            dy = off / 3; dx = off - dy * 3; rr = r + dy - 1;
            if ((unsigned)rr > 255u) continue;
        }
        const size_t rowpix = (size_t)(b * HW) + (size_t)rr * W;   // shifted row base pixel
#pragma unroll 1
        for (int icc = 0; icc < 8; ++icc) {
            __syncthreads();   // previous chunk's frag reads done
            // ---- stage A (exact image copy from packed weights) ----
            const char* Ag = (const char*)Wp +
                ((size_t)(((off * 2 + oct) * 8 + icc)) * 4096) * 2 + wv * 2048 + l * 16;
            gld_lds16(Ag, AsB);
            gld_lds16(Ag + 1024, AsB + 1024);
            // ---- stage B (NHWC gather, 16B per lane) ----
            const int ic0 = icc * 32;
#pragma unroll
            for (int i = 0; i < 2; i++) {
                const int px = spx_base + i * 16;
                const int cx = px0 + px + dx - 1;
                const void* g;
                if (NOFF == 9 && (unsigned)cx > 255u)
                    g = (const void*)zbuf;
                else
                    g = (const void*)(xT + ((rowpix + cx) * C + ic0 + skk0));
                gld_lds16(g, BsB + i * 1024);
            }
            asm volatile("s_waitcnt vmcnt(0)" ::: "memory");
            __syncthreads();
            // ---- fragments + 16 MFMAs ----
            bf16x8 af[4], bfr[4];
#pragma unroll
            for (int i = 0; i < 4; i++) af[i]  = *(const bf16x8*)((const char*)As + a_off[i]);
#pragma unroll
            for (int i = 0; i < 4; i++) bfr[i] = *(const bf16x8*)((const char*)Bs + b_off[i]);
#pragma unroll
            for (int mi = 0; mi < 4; mi++)
#pragma unroll
                for (int nj = 0; nj < 4; nj++)
                    acc[mi][nj] = __builtin_amdgcn_mfma_f32_16x16x32_bf16(
                        af[mi], bfr[nj], acc[mi][nj], 0, 0, 0);
        }
    }

    // ---- epilogue: C/D layout col=lane&15, row=(lane>>4)*4+reg ----
    const int colpx = px0 + wn + (l & 15);
    const int rowoc = oct * 128 + wm + (l >> 4) * 4;
#pragma unroll
    for (int mi = 0; mi < 4; mi++) {
#pragma unroll
        for (int nj = 0; nj < 4; nj++) {
#pragma unroll
            for (int rg = 0; rg < 4; rg++) {
                const int oc = rowoc + mi * 16 + rg;
                const int px = colpx + nj * 16;
                const size_t idx = ((size_t)(b * C + oc)) * HW + (size_t)r * W + px;
                if (F32OUT) outf[idx] = acc[mi][nj][rg];
                else        outb[idx] = f2bf(acc[mi][nj][rg]);
            }
        }
    }
}

// ---------------------------------------------------------------------------
// BN stats over (B,H,W) from NCHW bf16; writes fused scale/shift
// ---------------------------------------------------------------------------
__global__ __launch_bounds__(256) void bnstats_k(
    const unsigned short* __restrict__ a, const float* __restrict__ g,
    const float* __restrict__ beta, float* __restrict__ scale, float* __restrict__ shift)
{
    const int c = blockIdx.x;
    const int t = threadIdx.x;
    float s = 0.f, ss = 0.f;
    for (int b = 0; b < Bn; b++) {
        const uint4* p = (const uint4*)(a + ((size_t)(b * C + c)) * HW);
        for (int i = t; i < HW / 8; i += 256) {
            uint4 v = p[i];
            float f0 = bflo(v.x), f1 = bfhi(v.x), f2 = bflo(v.y), f3 = bfhi(v.y);
            float f4 = bflo(v.z), f5 = bfhi(v.z), f6 = bflo(v.w), f7 = bfhi(v.w);
            s  += (f0 + f1) + (f2 + f3) + (f4 + f5) + (f6 + f7);
            ss += f0*f0 + f1*f1 + f2*f2 + f3*f3 + f4*f4 + f5*f5 + f6*f6 + f7*f7;
        }
    }
    __shared__ float rs[256], rss[256];
    rs[t] = s; rss[t] = ss;
    __syncthreads();
    for (int o = 128; o > 0; o >>= 1) {
        if (t < o) { rs[t] += rs[t + o]; rss[t] += rss[t + o]; }
        __syncthreads();
    }
    if (t == 0) {
        const float n    = (float)Bn * HW;
        const float mean = rs[0] / n;
        const float var  = rss[0] / n - mean * mean;
        const float sc   = g[c] * rsqrtf(var + 1e-5f);
        scale[c] = sc;
        shift[c] = beta[c] - mean * sc;
    }
}

// ---------------------------------------------------------------------------
// depthwise 3x3 with BN+relu6 fused on input read.
// In: NCHW bf16 conv raw.  Out: NHWC bf16.
// Block: 64c x 64px (one row segment). grid = 2*256*4*4 = 8192
//   id: ct = id&3 (c0), wseg = (id>>2)&3 (w0), r = (id>>4)&255, b = id>>12
// ---------------------------------------------------------------------------
__global__ __launch_bounds__(256) void dwconv_k(
    const unsigned short* __restrict__ a, const float* __restrict__ scale,
    const float* __restrict__ shift, const float* __restrict__ wd,
    unsigned short* __restrict__ out)
{
    __shared__ float tile[64][3][67];   // cols w0-1 .. w0+65 -> idx 0..65
    __shared__ float wds[64 * 9];
    __shared__ float sscl[64], sshf[64];

    const int id = blockIdx.x;
    const int c0 = (id & 3) * 64;
    const int w0 = ((id >> 2) & 3) * 64;
    const int r  = (id >> 4) & 255;
    const int b  = id >> 12;
    const int t  = threadIdx.x;

    for (int i = t; i < 576; i += 256) wds[i] = wd[c0 * 9 + i];
    if (t < 64) { sscl[t] = scale[c0 + t]; sshf[t] = shift[c0 + t]; }
    __syncthreads();

    // main staging: 64c x 3row x 16seg of 4 elems
    for (int i = t; i < 3072; i += 256) {
        const int c   = i / 48;
        const int rem = i - c * 48;
        const int row = rem >> 4, seg = rem & 15;
        const int rr  = r + row - 1;
        float f0 = 0.f, f1 = 0.f, f2 = 0.f, f3 = 0.f;
        if ((unsigned)rr < 256u) {
            const uint2 v = *(const uint2*)(a + ((size_t)(b * C + c0 + c)) * HW
                                              + (size_t)rr * W + w0 + seg * 4);
            const float sc = sscl[c], sh = sshf[c];
            f0 = fminf(fmaxf(fmaf(bflo(v.x), sc, sh), 0.f), 6.f);
            f1 = fminf(fmaxf(fmaf(bfhi(v.x), sc, sh), 0.f), 6.f);
            f2 = fminf(fmaxf(fmaf(bflo(v.y), sc, sh), 0.f), 6.f);
            f3 = fminf(fmaxf(fmaf(bfhi(v.y), sc, sh), 0.f), 6.f);
        }
        float* dst = &tile[c][row][1 + seg * 4];
        dst[0] = f0; dst[1] = f1; dst[2] = f2; dst[3] = f3;
    }
    // edges: 64c x 3row x 2side
    for (int i = t; i < 384; i += 256) {
        const int c   = i / 6;
        const int rem = i - c * 6;
        const int row = rem >> 1, side = rem & 1;
        const int rr  = r + row - 1;
        const int col = side ? (w0 + 64) : (w0 - 1);
        float v = 0.f;
        if ((unsigned)rr < 256u && (unsigned)col < 256u) {
            float u = bf2f(a[((size_t)(b * C + c0 + c)) * HW + (size_t)rr * W + col]);
            v = fminf(fmaxf(fmaf(u, sscl[c], sshf[c]), 0.f), 6.f);
        }
        tile[c][row][side ? 65 : 0] = v;
    }
    __syncthreads();

    const int px = t >> 2, csub = t & 3;
    __attribute__((aligned(16))) unsigned short res[16];
#pragma unroll
    for (int k = 0; k < 16; k++) {
        const int c = csub * 16 + k;
        const float* wp = &wds[c * 9];
        float accv = 0.f;
#pragma unroll
        for (int dy = 0; dy < 3; dy++)
#pragma unroll
            for (int dx = 0; dx < 3; dx++)
                accv = fmaf(tile[c][dy][px + dx], wp[dy * 3 + dx], accv);
        res[k] = f2bf(accv);
    }
    unsigned short* o = out + ((size_t)(b * HW) + (size_t)r * W + w0 + px) * C + c0 + csub * 16;
    *(uint4*)o       = *(const uint4*)&res[0];
    *(uint4*)(o + 8) = *(const uint4*)&res[8];
}

// ---------------------------------------------------------------------------
// per-pixel channel mean from NHWC bf16.  4 threads per pixel.
// grid = 131072/64 = 2048, block 256
// ---------------------------------------------------------------------------
__global__ __launch_bounds__(256) void cmean_k(
    const unsigned short* __restrict__ m, float* __restrict__ s)
{
    const int t = threadIdx.x;
    const size_t px = (size_t)blockIdx.x * 64 + (t >> 2);
    const int csub = t & 3;
    const uint4* p = (const uint4*)(m + px * C + csub * 64);
    float acc = 0.f;
#pragma unroll
    for (int i = 0; i < 8; i++) {
        uint4 v = p[i];
        acc += (bflo(v.x) + bfhi(v.x)) + (bflo(v.y) + bfhi(v.y))
             + (bflo(v.z) + bfhi(v.z)) + (bflo(v.w) + bfhi(v.w));
    }
    acc += __shfl_xor(acc, 1);
    acc += __shfl_xor(acc, 2);
    if (csub == 0) s[px] = acc * (1.f / C);
}

// ---------------------------------------------------------------------------
// windowed attention. One wave per (b, head, wy, wx).
// q,k,v: NCHW bf16.  out: NHWC bf16.
// ---------------------------------------------------------------------------
__global__ __launch_bounds__(64) void attn_k(
    const unsigned short* __restrict__ q, const unsigned short* __restrict__ k,
    const unsigned short* __restrict__ v, const float* __restrict__ si,
    const float* __restrict__ sn, const float* __restrict__ temp,
    unsigned short* __restrict__ out)
{
    __shared__ __align__(16) float ks[64][36];
    __shared__ __align__(16) float vs[64][36];
    __shared__ float kscale[64];

    const int id   = blockIdx.x;
    const int wx   = id & 31;
    const int wy   = (id >> 5) & 31;
    const int head = (id >> 10) & 7;
    const int b    = id >> 13;
    const int t    = threadIdx.x;
    const int iy   = t >> 3, ix = t & 7;
    const int pix  = (wy * 8 + iy) * W + wx * 8 + ix;
    const int ch0  = head * 32;

    const unsigned short* qb = q + ((size_t)(b * C + ch0)) * HW + pix;
    const unsigned short* kb = k + ((size_t)(b * C + ch0)) * HW + pix;
    const unsigned short* vb = v + ((size_t)(b * C + ch0)) * HW + pix;

    float qr[32];
    float qss = 0.f, kss = 0.f;
#pragma unroll
    for (int dc = 0; dc < 32; dc++) {
        qr[dc] = bf2f(qb[(size_t)dc * HW]);
        qss += qr[dc] * qr[dc];
        float kvv = bf2f(kb[(size_t)dc * HW]);
        kss += kvv * kvv;
        ks[t][dc] = kvv;
        vs[t][dc] = bf2f(vb[(size_t)dc * HW]);
    }
    const float il = si[(size_t)b * HW + pix];
    const float nz = sn[(size_t)b * HW + pix];
    const float tscale = temp[head] * 0.17677669529663689f;  // 32^-0.5
    const float qmul = (1.f + il) / fmaxf(sqrtf(qss), 1e-12f) * tscale;
    kscale[t] = fminf(fmaxf(1.f - nz, 0.f), 1.f) / fmaxf(sqrtf(kss), 1e-12f);
    __syncthreads();

    float Srow[64];
#pragma unroll
    for (int kk = 0; kk < 64; kk++) {
        const float4* kr = (const float4*)(&ks[kk][0]);
        float d = 0.f;
#pragma unroll
        for (int j = 0; j < 8; j++) {
            float4 kv = kr[j];
            d = fmaf(qr[4 * j + 0], kv.x, d);
            d = fmaf(qr[4 * j + 1], kv.y, d);
            d = fmaf(qr[4 * j + 2], kv.z, d);
            d = fmaf(qr[4 * j + 3], kv.w, d);
        }
        Srow[kk] = d * qmul * kscale[kk];
    }
    float m = Srow[0];
#pragma unroll
    for (int kk = 1; kk < 64; kk++) m = fmaxf(m, Srow[kk]);
    float ssum = 0.f;
#pragma unroll
    for (int kk = 0; kk < 64; kk++) {
        float e = __expf(Srow[kk] - m);
        Srow[kk] = e;
        ssum += e;
    }
    const float inv = 1.f / ssum;

    float4 oacc[8];
#pragma unroll
    for (int j = 0; j < 8; j++) oacc[j] = make_float4(0.f, 0.f, 0.f, 0.f);
#pragma unroll
    for (int kk = 0; kk < 64; kk++) {
        const float p = Srow[kk] * inv;
        const float4* vr = (const float4*)(&vs[kk][0]);
#pragma unroll
        for (int j = 0; j < 8; j++) {
            float4 vv = vr[j];
            oacc[j].x = fmaf(p, vv.x, oacc[j].x);
            oacc[j].y = fmaf(p, vv.y, oacc[j].y);
            oacc[j].z = fmaf(p, vv.z, oacc[j].z);
            oacc[j].w = fmaf(p, vv.w, oacc[j].w);
        }
    }
    // NHWC bf16 write: 32 contiguous channels
    __attribute__((aligned(16))) unsigned short ov[32];
#pragma unroll
    for (int j = 0; j < 8; j++) {
        ov[4 * j + 0] = f2bf(oacc[j].x);
        ov[4 * j + 1] = f2bf(oacc[j].y);
        ov[4 * j + 2] = f2bf(oacc[j].z);
        ov[4 * j + 3] = f2bf(oacc[j].w);
    }
    unsigned short* ob = out + ((size_t)(b * HW) + pix) * C + ch0;
    *(uint4*)(ob +  0) = *(const uint4*)&ov[0];
    *(uint4*)(ob +  8) = *(const uint4*)&ov[8];
    *(uint4*)(ob + 16) = *(const uint4*)&ov[16];
    *(uint4*)(ob + 24) = *(const uint4*)&ov[24];
}

// ---------------------------------------------------------------------------
extern "C" void kernel_launch(void* const* d_in, const int* in_sizes, int n_in,
                              void* d_out, int out_size, void* d_ws, size_t ws_size,
                              hipStream_t stream)
{
    const float* x        = (const float*)d_in[0];
    const float* w_iem    = (const float*)d_in[1];
    const float* g_iem    = (const float*)d_in[2];
    const float* b_iem    = (const float*)d_in[3];
    const float* w_nem    = (const float*)d_in[4];
    const float* g_nem    = (const float*)d_in[5];
    const float* b_nem    = (const float*)d_in[6];
    const float* w_iem_dw = (const float*)d_in[7];
    const float* w_nem_dw = (const float*)d_in[8];
    const float* w_q      = (const float*)d_in[9];
    const float* w_k      = (const float*)d_in[10];
    const float* w_v      = (const float*)d_in[11];
    const float* w_proj   = (const float*)d_in[12];
    const float* temp     = (const float*)d_in[13];

    // workspace carve-up (bytes)
    char* p = (char*)d_ws;
    unsigned short* zbuf = (unsigned short*)p;      p += 256;
    float* scl = (float*)p;                         p += 256 * 4;
    float* shf = (float*)p;                         p += 256 * 4;
    float* sI  = (float*)p;                         p += (size_t)Bn * HW * 4;
    float* sN  = (float*)p;                         p += (size_t)Bn * HW * 4;
    unsigned short* Wp_iem = (unsigned short*)p;    p += 589824 * 2;
    unsigned short* Wp_nem = (unsigned short*)p;    p += 589824 * 2;
    unsigned short* Wpq = (unsigned short*)p;       p += 65536 * 2;
    unsigned short* Wpk = (unsigned short*)p;       p += 65536 * 2;
    unsigned short* Wpv = (unsigned short*)p;       p += 65536 * 2;
    unsigned short* Wpp = (unsigned short*)p;       p += 65536 * 2;
    unsigned short* xT   = (unsigned short*)p;      p += Bn * CHW * 2;  // NHWC bf16
    unsigned short* bufA = (unsigned short*)p;      p += Bn * CHW * 2;  // conv raw / Q (NCHW)
    unsigned short* Ibf  = (unsigned short*)p;      p += Bn * CHW * 2;  // illum NHWC / K (NCHW)
    unsigned short* Nbf  = (unsigned short*)p;      p += Bn * CHW * 2;  // noise NHWC / V (NCHW)
    unsigned short* Obf  = (unsigned short*)p;      p += Bn * CHW * 2;  // attn out NHWC

    hipMemsetAsync(zbuf, 0, 256, stream);

    packx_k<<<8192, 256, 0, stream>>>(x, xT);
    pack_k<<<2304, 256, 0, stream>>>(w_iem, Wp_iem, 9);
    pack_k<<<2304, 256, 0, stream>>>(w_nem, Wp_nem, 9);
    pack_k<<<256, 256, 0, stream>>>(w_q, Wpq, 1);
    pack_k<<<256, 256, 0, stream>>>(w_k, Wpk, 1);
    pack_k<<<256, 256, 0, stream>>>(w_v, Wpv, 1);
    pack_k<<<256, 256, 0, stream>>>(w_proj, Wpp, 1);

    // IEM path
    gemm_k<9, false><<<2048, 256, 0, stream>>>(xT, Wp_iem, bufA, nullptr, zbuf);
    bnstats_k<<<256, 256, 0, stream>>>(bufA, g_iem, b_iem, scl, shf);
    dwconv_k<<<8192, 256, 0, stream>>>(bufA, scl, shf, w_iem_dw, Ibf);
    // NEM path
    gemm_k<9, false><<<2048, 256, 0, stream>>>(xT, Wp_nem, bufA, nullptr, zbuf);
    bnstats_k<<<256, 256, 0, stream>>>(bufA, g_nem, b_nem, scl, shf);
    dwconv_k<<<8192, 256, 0, stream>>>(bufA, scl, shf, w_nem_dw, Nbf);

    cmean_k<<<2048, 256, 0, stream>>>(Ibf, sI);
    cmean_k<<<2048, 256, 0, stream>>>(Nbf, sN);

    // projections (NCHW bf16 outputs)
    gemm_k<1, false><<<2048, 256, 0, stream>>>(Ibf, Wpq, bufA, nullptr, zbuf);  // Q
    gemm_k<1, false><<<2048, 256, 0, stream>>>(Nbf, Wpk, Ibf, nullptr, zbuf);   // K
    gemm_k<1, false><<<2048, 256, 0, stream>>>(xT,  Wpv, Nbf, nullptr, zbuf);   // V

    attn_k<<<16384, 64, 0, stream>>>(bufA, Ibf, Nbf, sI, sN, temp, Obf);

    // final projection -> fp32 d_out
    gemm_k<1, true><<<2048, 256, 0, stream>>>(Obf, Wpp, nullptr, (float*)d_out, zbuf);
}

// Round 3
// 1350.007 us; speedup vs baseline: 7.0020x; 1.1110x over previous
//
#include <hip/hip_runtime.h>
#include <math.h>

// ---------------------------------------------------------------------------
// Problem constants
constexpr int Bn  = 2;
constexpr int C   = 256;
constexpr int H   = 256;
constexpr int W   = 256;
constexpr int HW  = H * W;          // 65536
constexpr size_t CHW = (size_t)C * HW;

typedef __bf16 bf16x8 __attribute__((ext_vector_type(8)));
typedef float  f32x4  __attribute__((ext_vector_type(4)));

// fp32 -> bf16 round-to-nearest-even
__device__ __forceinline__ unsigned short f2bf(float f) {
    unsigned int u = __float_as_uint(f);
    u += 0x7fffu + ((u >> 16) & 1u);
    return (unsigned short)(u >> 16);
}
__device__ __forceinline__ float bf2f(unsigned short h) {
    return __uint_as_float(((unsigned int)h) << 16);
}
// two bf16 packed in a uint -> floats (hi needs only a mask)
__device__ __forceinline__ float bflo(unsigned int u) { return __uint_as_float(u << 16); }
__device__ __forceinline__ float bfhi(unsigned int u) { return __uint_as_float(u & 0xffff0000u); }

// async global->LDS, 16B per lane; LDS dest = uniform base + lane*16
__device__ __forceinline__ void gld_lds16(const void* g, void* lds) {
    __builtin_amdgcn_global_load_lds(
        (const __attribute__((address_space(1))) unsigned int*)g,
        (__attribute__((address_space(3))) unsigned int*)lds, 16, 0, 0);
}

// ---------------------------------------------------------------------------
// packx: x fp32 NCHW -> bf16 NHWC.  Tile 64c x 64px via LDS transpose.
// grid = (2*65536/64) * 4 = 8192 blocks
// ---------------------------------------------------------------------------
__global__ __launch_bounds__(256) void packx_k(
    const float* __restrict__ x, unsigned short* __restrict__ xT)
{
    __shared__ float tl[64][65];
    const int id = blockIdx.x;
    const int ct = id & 3;
    const size_t px0 = (size_t)(id >> 2) * 64;   // global pixel (incl batch)
    const int b  = (int)(px0 >> 16);
    const int hw = (int)(px0 & 65535);
    const int c0 = ct * 64;
    const int t  = threadIdx.x;

    {   // load: thread (cl, pseg): 16 px of channel cl
        const int cl = t >> 2, pseg = t & 3;
        const float* src = x + ((size_t)(b * C + c0 + cl)) * HW + hw + pseg * 16;
#pragma unroll
        for (int i = 0; i < 4; i++) {
            float4 v = *(const float4*)(src + i * 4);
            tl[cl][pseg * 16 + i * 4 + 0] = v.x;
            tl[cl][pseg * 16 + i * 4 + 1] = v.y;
            tl[cl][pseg * 16 + i * 4 + 2] = v.z;
            tl[cl][pseg * 16 + i * 4 + 3] = v.w;
        }
    }
    __syncthreads();
    {   // store: thread (pl, csec): 16 channels of pixel pl, contiguous in NHWC
        const int pl = t >> 2, csec = t & 3;
        __attribute__((aligned(16))) unsigned short rv[16];
#pragma unroll
        for (int j = 0; j < 16; j++) rv[j] = f2bf(tl[csec * 16 + j][pl]);
        unsigned short* dst = xT + (px0 + pl) * C + c0 + csec * 16;
        *(uint4*)dst       = *(const uint4*)&rv[0];
        *(uint4*)(dst + 8) = *(const uint4*)&rv[8];
    }
}

// ---------------------------------------------------------------------------
// pack weights into the LDS image the GEMM stages:
// layout [taps][oct(2)][icc(8)][ocl(128)][kslot(32)], with XOR-4 swizzle
// content(ocl, kslot) = W[oc][ icc*32 + ((kslot>>3) ^ ((ocl>>2)&3))*8 + (kslot&7) ]
// ---------------------------------------------------------------------------
__global__ __launch_bounds__(256) void pack_k(
    const float* __restrict__ w, unsigned short* __restrict__ out, int taps)
{
    const int e = blockIdx.x * 256 + threadIdx.x;
    const int kslot = e & 31;
    const int ocl   = (e >> 5) & 127;
    const int icc   = (e >> 12) & 7;
    const int oct   = (e >> 15) & 1;
    const int off   = e >> 16;
    const int oc = oct * 128 + ocl;
    const int q  = kslot >> 3, j = kslot & 7;
    const int ic = icc * 32 + ((q ^ ((ocl >> 2) & 3)) << 3) + j;
    out[e] = f2bf(w[((size_t)oc * C + ic) * taps + off]);
}

// ---------------------------------------------------------------------------
// MFMA GEMM: out[oc][px] = sum_k Wp[oc][k] * B[k][px]
//  NOFF==9: implicit 3x3 conv (K = 256ic x 9 taps), B = xT shifted (zero pad)
//  NOFF==1: 1x1 conv (K = 256)
// B input: NHWC bf16.  Output: NCHW bf16 / NCHW fp32 / NHWC bf16.
// Block: 256 thr = 4 waves (2x2), tile 128oc x 128px (one image row segment).
// grid = 2048:  id = oct | ch<<1 | r<<2 | b<<10
// ---------------------------------------------------------------------------
template<int NOFF, bool F32OUT, bool NHWC_OUT>
__global__ __launch_bounds__(256, 2) void gemm_k(
    const unsigned short* __restrict__ xT, const unsigned short* __restrict__ Wp,
    unsigned short* __restrict__ outb, float* __restrict__ outf,
    const unsigned short* __restrict__ zbuf)
{
    __shared__ unsigned short As[128 * 32];   // [ocl][kslot]  8KB
    __shared__ unsigned short Bs[128 * 32];   // [px][kslot]   8KB

    const int id  = blockIdx.x;
    const int oct = id & 1;
    const int ch  = (id >> 1) & 1;
    const int r   = (id >> 2) & 255;
    const int b   = id >> 10;
    const int px0 = ch * 128;

    const int t  = threadIdx.x;
    const int wv = t >> 6;
    const int l  = t & 63;
    const int wm = (wv >> 1) * 64;
    const int wn = (wv & 1) * 64;

    // swizzled quad for frag reads
    const int qp = (l >> 4) ^ ((l >> 2) & 3);
    int a_off[4], b_off[4];
#pragma unroll
    for (int i = 0; i < 4; i++) {
        a_off[i] = (wm + i * 16 + (l & 15)) * 64 + qp * 16;   // bytes
        b_off[i] = (wn + i * 16 + (l & 15)) * 64 + qp * 16;
    }
    // B staging: lane l stages LDS slot row px=(wv*32+i*16+(l>>2)), quad (l&3)
    const int spx_base = wv * 32 + (l >> 2);
    const int skk0 = (((l & 3) ^ (l >> 4)) << 3);            // source k-group (elems)

    f32x4 acc[4][4];
#pragma unroll
    for (int i = 0; i < 4; i++)
#pragma unroll
        for (int j = 0; j < 4; j++) acc[i][j] = (f32x4){0.f, 0.f, 0.f, 0.f};

    char* AsB = (char*)As + wv * 2048;
    char* BsB = (char*)Bs + wv * 2048;

#pragma unroll 1
    for (int off = 0; off < NOFF; ++off) {
        int dy = 1, dx = 1, rr = r;
        if (NOFF == 9) {
            dy = off / 3; dx = off - dy * 3; rr = r + dy - 1;
            if ((unsigned)rr > 255u) continue;
        }
        const size_t rowpix = (size_t)(b * HW) + (size_t)rr * W;   // shifted row base pixel
#pragma unroll 1
        for (int icc = 0; icc < 8; ++icc) {
            __syncthreads();   // previous chunk's frag reads done
            // ---- stage A (exact image copy from packed weights) ----
            const char* Ag = (const char*)Wp +
                ((size_t)(((off * 2 + oct) * 8 + icc)) * 4096) * 2 + wv * 2048 + l * 16;
            gld_lds16(Ag, AsB);
            gld_lds16(Ag + 1024, AsB + 1024);
            // ---- stage B (NHWC gather, 16B per lane) ----
            const int ic0 = icc * 32;
#pragma unroll
            for (int i = 0; i < 2; i++) {
                const int px = spx_base + i * 16;
                const int cx = px0 + px + dx - 1;
                const void* g;
                if (NOFF == 9 && (unsigned)cx > 255u)
                    g = (const void*)zbuf;
                else
                    g = (const void*)(xT + ((rowpix + cx) * C + ic0 + skk0));
                gld_lds16(g, BsB + i * 1024);
            }
            asm volatile("s_waitcnt vmcnt(0)" ::: "memory");
            __syncthreads();
            // ---- fragments + 16 MFMAs ----
            bf16x8 af[4], bfr[4];
#pragma unroll
            for (int i = 0; i < 4; i++) af[i]  = *(const bf16x8*)((const char*)As + a_off[i]);
#pragma unroll
            for (int i = 0; i < 4; i++) bfr[i] = *(const bf16x8*)((const char*)Bs + b_off[i]);
#pragma unroll
            for (int mi = 0; mi < 4; mi++)
#pragma unroll
                for (int nj = 0; nj < 4; nj++)
                    acc[mi][nj] = __builtin_amdgcn_mfma_f32_16x16x32_bf16(
                        af[mi], bfr[nj], acc[mi][nj], 0, 0, 0);
        }
    }

    // ---- epilogue: C/D layout col=lane&15, row=(lane>>4)*4+reg ----
    const int colpx = px0 + wn + (l & 15);
    const int rowoc = oct * 128 + wm + (l >> 4) * 4;
    if (NHWC_OUT) {
        // bf16 NHWC: 4 accumulator regs = 4 consecutive oc = contiguous 8B
        const size_t pxg = (size_t)(b * HW) + (size_t)r * W;
#pragma unroll
        for (int mi = 0; mi < 4; mi++) {
#pragma unroll
            for (int nj = 0; nj < 4; nj++) {
                __attribute__((aligned(8))) unsigned short rv[4];
#pragma unroll
                for (int rg = 0; rg < 4; rg++) rv[rg] = f2bf(acc[mi][nj][rg]);
                const int oc = rowoc + mi * 16;
                const int px = colpx + nj * 16;
                *(uint2*)(outb + (pxg + px) * C + oc) = *(const uint2*)rv;
            }
        }
    } else {
#pragma unroll
        for (int mi = 0; mi < 4; mi++) {
#pragma unroll
            for (int nj = 0; nj < 4; nj++) {
#pragma unroll
                for (int rg = 0; rg < 4; rg++) {
                    const int oc = rowoc + mi * 16 + rg;
                    const int px = colpx + nj * 16;
                    const size_t idx = ((size_t)(b * C + oc)) * HW + (size_t)r * W + px;
                    if (F32OUT) outf[idx] = acc[mi][nj][rg];
                    else        outb[idx] = f2bf(acc[mi][nj][rg]);
                }
            }
        }
    }
}

// ---------------------------------------------------------------------------
// BN stats over (B,H,W) from NCHW bf16; writes fused scale/shift
// ---------------------------------------------------------------------------
__global__ __launch_bounds__(256) void bnstats_k(
    const unsigned short* __restrict__ a, const float* __restrict__ g,
    const float* __restrict__ beta, float* __restrict__ scale, float* __restrict__ shift)
{
    const int c = blockIdx.x;
    const int t = threadIdx.x;
    float s = 0.f, ss = 0.f;
    for (int b = 0; b < Bn; b++) {
        const uint4* p = (const uint4*)(a + ((size_t)(b * C + c)) * HW);
        for (int i = t; i < HW / 8; i += 256) {
            uint4 v = p[i];
            float f0 = bflo(v.x), f1 = bfhi(v.x), f2 = bflo(v.y), f3 = bfhi(v.y);
            float f4 = bflo(v.z), f5 = bfhi(v.z), f6 = bflo(v.w), f7 = bfhi(v.w);
            s  += (f0 + f1) + (f2 + f3) + (f4 + f5) + (f6 + f7);
            ss += f0*f0 + f1*f1 + f2*f2 + f3*f3 + f4*f4 + f5*f5 + f6*f6 + f7*f7;
        }
    }
    __shared__ float rs[256], rss[256];
    rs[t] = s; rss[t] = ss;
    __syncthreads();
    for (int o = 128; o > 0; o >>= 1) {
        if (t < o) { rs[t] += rs[t + o]; rss[t] += rss[t + o]; }
        __syncthreads();
    }
    if (t == 0) {
        const float n    = (float)Bn * HW;
        const float mean = rs[0] / n;
        const float var  = rss[0] / n - mean * mean;
        const float sc   = g[c] * rsqrtf(var + 1e-5f);
        scale[c] = sc;
        shift[c] = beta[c] - mean * sc;
    }
}

// ---------------------------------------------------------------------------
// depthwise 3x3 with BN+relu6 fused on input read.
// In: NCHW bf16 conv raw.  Out: NHWC bf16.
// Block: 64c x 64px (one row segment). grid = 2*256*4*4 = 8192
//   id: ct = id&3 (c0), wseg = (id>>2)&3 (w0), r = (id>>4)&255, b = id>>12
// ---------------------------------------------------------------------------
__global__ __launch_bounds__(256) void dwconv_k(
    const unsigned short* __restrict__ a, const float* __restrict__ scale,
    const float* __restrict__ shift, const float* __restrict__ wd,
    unsigned short* __restrict__ out)
{
    __shared__ float tile[64][3][67];   // cols w0-1 .. w0+65 -> idx 0..65
    __shared__ float wds[64 * 9];
    __shared__ float sscl[64], sshf[64];

    const int id = blockIdx.x;
    const int c0 = (id & 3) * 64;
    const int w0 = ((id >> 2) & 3) * 64;
    const int r  = (id >> 4) & 255;
    const int b  = id >> 12;
    const int t  = threadIdx.x;

    for (int i = t; i < 576; i += 256) wds[i] = wd[c0 * 9 + i];
    if (t < 64) { sscl[t] = scale[c0 + t]; sshf[t] = shift[c0 + t]; }
    __syncthreads();

    // main staging: 64c x 3row x 16seg of 4 elems
    for (int i = t; i < 3072; i += 256) {
        const int c   = i / 48;
        const int rem = i - c * 48;
        const int row = rem >> 4, seg = rem & 15;
        const int rr  = r + row - 1;
        float f0 = 0.f, f1 = 0.f, f2 = 0.f, f3 = 0.f;
        if ((unsigned)rr < 256u) {
            const uint2 v = *(const uint2*)(a + ((size_t)(b * C + c0 + c)) * HW
                                              + (size_t)rr * W + w0 + seg * 4);
            const float sc = sscl[c], sh = sshf[c];
            f0 = fminf(fmaxf(fmaf(bflo(v.x), sc, sh), 0.f), 6.f);
            f1 = fminf(fmaxf(fmaf(bfhi(v.x), sc, sh), 0.f), 6.f);
            f2 = fminf(fmaxf(fmaf(bflo(v.y), sc, sh), 0.f), 6.f);
            f3 = fminf(fmaxf(fmaf(bfhi(v.y), sc, sh), 0.f), 6.f);
        }
        float* dst = &tile[c][row][1 + seg * 4];
        dst[0] = f0; dst[1] = f1; dst[2] = f2; dst[3] = f3;
    }
    // edges: 64c x 3row x 2side
    for (int i = t; i < 384; i += 256) {
        const int c   = i / 6;
        const int rem = i - c * 6;
        const int row = rem >> 1, side = rem & 1;
        const int rr  = r + row - 1;
        const int col = side ? (w0 + 64) : (w0 - 1);
        float v = 0.f;
        if ((unsigned)rr < 256u && (unsigned)col < 256u) {
            float u = bf2f(a[((size_t)(b * C + c0 + c)) * HW + (size_t)rr * W + col]);
            v = fminf(fmaxf(fmaf(u, sscl[c], sshf[c]), 0.f), 6.f);
        }
        tile[c][row][side ? 65 : 0] = v;
    }
    __syncthreads();

    const int px = t >> 2, csub = t & 3;
    __attribute__((aligned(16))) unsigned short res[16];
#pragma unroll
    for (int k = 0; k < 16; k++) {
        const int c = csub * 16 + k;
        const float* wp = &wds[c * 9];
        float accv = 0.f;
#pragma unroll
        for (int dy = 0; dy < 3; dy++)
#pragma unroll
            for (int dx = 0; dx < 3; dx++)
                accv = fmaf(tile[c][dy][px + dx], wp[dy * 3 + dx], accv);
        res[k] = f2bf(accv);
    }
    unsigned short* o = out + ((size_t)(b * HW) + (size_t)r * W + w0 + px) * C + c0 + csub * 16;
    *(uint4*)o       = *(const uint4*)&res[0];
    *(uint4*)(o + 8) = *(const uint4*)&res[8];
}

// ---------------------------------------------------------------------------
// per-pixel channel mean from NHWC bf16.  4 threads per pixel.
// grid = 131072/64 = 2048, block 256
// ---------------------------------------------------------------------------
__global__ __launch_bounds__(256) void cmean_k(
    const unsigned short* __restrict__ m, float* __restrict__ s)
{
    const int t = threadIdx.x;
    const size_t px = (size_t)blockIdx.x * 64 + (t >> 2);
    const int csub = t & 3;
    const uint4* p = (const uint4*)(m + px * C + csub * 64);
    float acc = 0.f;
#pragma unroll
    for (int i = 0; i < 8; i++) {
        uint4 v = p[i];
        acc += (bflo(v.x) + bfhi(v.x)) + (bflo(v.y) + bfhi(v.y))
             + (bflo(v.z) + bfhi(v.z)) + (bflo(v.w) + bfhi(v.w));
    }
    acc += __shfl_xor(acc, 1);
    acc += __shfl_xor(acc, 2);
    if (csub == 0) s[px] = acc * (1.f / C);
}

// ---------------------------------------------------------------------------
// windowed attention. One wave per (b, head, wy, wx).
// q,k,v: NHWC bf16 (channel-contiguous -> fully coalesced 64B/lane loads).
// out: NHWC bf16.
// ---------------------------------------------------------------------------
__global__ __launch_bounds__(64) void attn_k(
    const unsigned short* __restrict__ q, const unsigned short* __restrict__ k,
    const unsigned short* __restrict__ v, const float* __restrict__ si,
    const float* __restrict__ sn, const float* __restrict__ temp,
    unsigned short* __restrict__ out)
{
    __shared__ __align__(16) float ks[64][36];
    __shared__ __align__(16) float vs[64][36];
    __shared__ float kscale[64];

    const int id   = blockIdx.x;
    const int wx   = id & 31;
    const int wy   = (id >> 5) & 31;
    const int head = (id >> 10) & 7;
    const int b    = id >> 13;
    const int t    = threadIdx.x;
    const int iy   = t >> 3, ix = t & 7;
    const int pix  = (wy * 8 + iy) * W + wx * 8 + ix;
    const int ch0  = head * 32;

    const size_t pbase = ((size_t)(b * HW) + pix) * C + ch0;

    // ---- coalesced NHWC loads: 64B contiguous per lane per tensor ----
    float qr[32];
    float qss = 0.f, kss = 0.f;
    {
        const uint4* qp = (const uint4*)(q + pbase);
        const uint4* kp = (const uint4*)(k + pbase);
        const uint4* vp = (const uint4*)(v + pbase);
#pragma unroll
        for (int i = 0; i < 4; i++) {
            uint4 qv = qp[i];
            float* qd = &qr[i * 8];
            qd[0] = bflo(qv.x); qd[1] = bfhi(qv.x); qd[2] = bflo(qv.y); qd[3] = bfhi(qv.y);
            qd[4] = bflo(qv.z); qd[5] = bfhi(qv.z); qd[6] = bflo(qv.w); qd[7] = bfhi(qv.w);
#pragma unroll
            for (int j = 0; j < 8; j++) qss += qd[j] * qd[j];

            uint4 kv = kp[i];
            float kd[8];
            kd[0] = bflo(kv.x); kd[1] = bfhi(kv.x); kd[2] = bflo(kv.y); kd[3] = bfhi(kv.y);
            kd[4] = bflo(kv.z); kd[5] = bfhi(kv.z); kd[6] = bflo(kv.w); kd[7] = bfhi(kv.w);
#pragma unroll
            for (int j = 0; j < 8; j++) {
                kss += kd[j] * kd[j];
                ks[t][i * 8 + j] = kd[j];
            }
            uint4 vv = vp[i];
            vs[t][i * 8 + 0] = bflo(vv.x); vs[t][i * 8 + 1] = bfhi(vv.x);
            vs[t][i * 8 + 2] = bflo(vv.y); vs[t][i * 8 + 3] = bfhi(vv.y);
            vs[t][i * 8 + 4] = bflo(vv.z); vs[t][i * 8 + 5] = bfhi(vv.z);
            vs[t][i * 8 + 6] = bflo(vv.w); vs[t][i * 8 + 7] = bfhi(vv.w);
        }
    }
    const float il = si[(size_t)b * HW + pix];
    const float nz = sn[(size_t)b * HW + pix];
    const float tscale = temp[head] * 0.17677669529663689f;  // 32^-0.5
    const float qmul = (1.f + il) / fmaxf(sqrtf(qss), 1e-12f) * tscale;
    kscale[t] = fminf(fmaxf(1.f - nz, 0.f), 1.f) / fmaxf(sqrtf(kss), 1e-12f);
    __syncthreads();

    float Srow[64];
#pragma unroll
    for (int kk = 0; kk < 64; kk++) {
        const float4* kr = (const float4*)(&ks[kk][0]);
        float d = 0.f;
#pragma unroll
        for (int j = 0; j < 8; j++) {
            float4 kv = kr[j];
            d = fmaf(qr[4 * j + 0], kv.x, d);
            d = fmaf(qr[4 * j + 1], kv.y, d);
            d = fmaf(qr[4 * j + 2], kv.z, d);
            d = fmaf(qr[4 * j + 3], kv.w, d);
        }
        Srow[kk] = d * qmul * kscale[kk];
    }
    float m = Srow[0];
#pragma unroll
    for (int kk = 1; kk < 64; kk++) m = fmaxf(m, Srow[kk]);
    float ssum = 0.f;
#pragma unroll
    for (int kk = 0; kk < 64; kk++) {
        float e = __expf(Srow[kk] - m);
        Srow[kk] = e;
        ssum += e;
    }
    const float inv = 1.f / ssum;

    float4 oacc[8];
#pragma unroll
    for (int j = 0; j < 8; j++) oacc[j] = make_float4(0.f, 0.f, 0.f, 0.f);
#pragma unroll
    for (int kk = 0; kk < 64; kk++) {
        const float p = Srow[kk] * inv;
        const float4* vr = (const float4*)(&vs[kk][0]);
#pragma unroll
        for (int j = 0; j < 8; j++) {
            float4 vv = vr[j];
            oacc[j].x = fmaf(p, vv.x, oacc[j].x);
            oacc[j].y = fmaf(p, vv.y, oacc[j].y);
            oacc[j].z = fmaf(p, vv.z, oacc[j].z);
            oacc[j].w = fmaf(p, vv.w, oacc[j].w);
        }
    }
    // NHWC bf16 write: 32 contiguous channels
    __attribute__((aligned(16))) unsigned short ov[32];
#pragma unroll
    for (int j = 0; j < 8; j++) {
        ov[4 * j + 0] = f2bf(oacc[j].x);
        ov[4 * j + 1] = f2bf(oacc[j].y);
        ov[4 * j + 2] = f2bf(oacc[j].z);
        ov[4 * j + 3] = f2bf(oacc[j].w);
    }
    unsigned short* ob = out + pbase;
    *(uint4*)(ob +  0) = *(const uint4*)&ov[0];
    *(uint4*)(ob +  8) = *(const uint4*)&ov[8];
    *(uint4*)(ob + 16) = *(const uint4*)&ov[16];
    *(uint4*)(ob + 24) = *(const uint4*)&ov[24];
}

// ---------------------------------------------------------------------------
extern "C" void kernel_launch(void* const* d_in, const int* in_sizes, int n_in,
                              void* d_out, int out_size, void* d_ws, size_t ws_size,
                              hipStream_t stream)
{
    const float* x        = (const float*)d_in[0];
    const float* w_iem    = (const float*)d_in[1];
    const float* g_iem    = (const float*)d_in[2];
    const float* b_iem    = (const float*)d_in[3];
    const float* w_nem    = (const float*)d_in[4];
    const float* g_nem    = (const float*)d_in[5];
    const float* b_nem    = (const float*)d_in[6];
    const float* w_iem_dw = (const float*)d_in[7];
    const float* w_nem_dw = (const float*)d_in[8];
    const float* w_q      = (const float*)d_in[9];
    const float* w_k      = (const float*)d_in[10];
    const float* w_v      = (const float*)d_in[11];
    const float* w_proj   = (const float*)d_in[12];
    const float* temp     = (const float*)d_in[13];

    // workspace carve-up (bytes)
    char* p = (char*)d_ws;
    unsigned short* zbuf = (unsigned short*)p;      p += 256;
    float* scl = (float*)p;                         p += 256 * 4;
    float* shf = (float*)p;                         p += 256 * 4;
    float* sI  = (float*)p;                         p += (size_t)Bn * HW * 4;
    float* sN  = (float*)p;                         p += (size_t)Bn * HW * 4;
    unsigned short* Wp_iem = (unsigned short*)p;    p += 589824 * 2;
    unsigned short* Wp_nem = (unsigned short*)p;    p += 589824 * 2;
    unsigned short* Wpq = (unsigned short*)p;       p += 65536 * 2;
    unsigned short* Wpk = (unsigned short*)p;       p += 65536 * 2;
    unsigned short* Wpv = (unsigned short*)p;       p += 65536 * 2;
    unsigned short* Wpp = (unsigned short*)p;       p += 65536 * 2;
    unsigned short* xT   = (unsigned short*)p;      p += Bn * CHW * 2;  // NHWC bf16
    unsigned short* bufA = (unsigned short*)p;      p += Bn * CHW * 2;  // conv raw (NCHW) / Q (NHWC)
    unsigned short* Ibf  = (unsigned short*)p;      p += Bn * CHW * 2;  // illum NHWC / K (NHWC)
    unsigned short* Nbf  = (unsigned short*)p;      p += Bn * CHW * 2;  // noise NHWC / V (NHWC)
    unsigned short* Obf  = (unsigned short*)p;      p += Bn * CHW * 2;  // attn out NHWC

    hipMemsetAsync(zbuf, 0, 256, stream);

    packx_k<<<8192, 256, 0, stream>>>(x, xT);
    pack_k<<<2304, 256, 0, stream>>>(w_iem, Wp_iem, 9);
    pack_k<<<2304, 256, 0, stream>>>(w_nem, Wp_nem, 9);
    pack_k<<<256, 256, 0, stream>>>(w_q, Wpq, 1);
    pack_k<<<256, 256, 0, stream>>>(w_k, Wpk, 1);
    pack_k<<<256, 256, 0, stream>>>(w_v, Wpv, 1);
    pack_k<<<256, 256, 0, stream>>>(w_proj, Wpp, 1);

    // IEM path (conv raw stays NCHW for bnstats/dwconv)
    gemm_k<9, false, false><<<2048, 256, 0, stream>>>(xT, Wp_iem, bufA, nullptr, zbuf);
    bnstats_k<<<256, 256, 0, stream>>>(bufA, g_iem, b_iem, scl, shf);
    dwconv_k<<<8192, 256, 0, stream>>>(bufA, scl, shf, w_iem_dw, Ibf);
    // NEM path
    gemm_k<9, false, false><<<2048, 256, 0, stream>>>(xT, Wp_nem, bufA, nullptr, zbuf);
    bnstats_k<<<256, 256, 0, stream>>>(bufA, g_nem, b_nem, scl, shf);
    dwconv_k<<<8192, 256, 0, stream>>>(bufA, scl, shf, w_nem_dw, Nbf);

    cmean_k<<<2048, 256, 0, stream>>>(Ibf, sI);
    cmean_k<<<2048, 256, 0, stream>>>(Nbf, sN);

    // projections -> NHWC bf16 outputs (coalesced for attention)
    gemm_k<1, false, true><<<2048, 256, 0, stream>>>(Ibf, Wpq, bufA, nullptr, zbuf);  // Q
    gemm_k<1, false, true><<<2048, 256, 0, stream>>>(Nbf, Wpk, Ibf, nullptr, zbuf);   // K
    gemm_k<1, false, true><<<2048, 256, 0, stream>>>(xT,  Wpv, Nbf, nullptr, zbuf);   // V

    attn_k<<<16384, 64, 0, stream>>>(bufA, Ibf, Nbf, sI, sN, temp, Obf);

    // final projection -> fp32 d_out (NCHW)
    gemm_k<1, true, false><<<2048, 256, 0, stream>>>(Obf, Wpp, nullptr, (float*)d_out, zbuf);
}